// Round 1
// baseline (3415.757 us; speedup 1.0000x reference)
//
#include <hip/hip_runtime.h>

#define HID 256
#define NSPOT 20000
#define NCITY 2000
#define NWORD 20000

// ---------------------------------------------------------------------------
// wq[h][i] = sum_o W_att[h][i][o] * q_att[h][o]
__global__ void wq_kernel(const float* __restrict__ W, const float* __restrict__ q,
                          float* __restrict__ wq) {
    int idx = blockIdx.x * 256 + threadIdx.x;   // 4*512 = 2048
    if (idx >= 2048) return;
    int h = idx >> 9, i = idx & 511;
    const float* Wr = W + ((size_t)h * 512 + i) * 128;
    const float* qr = q + h * 128;
    float s = 0.f;
    #pragma unroll 4
    for (int o = 0; o < 128; o++) s += Wr[o] * qr[o];
    wq[idx] = s;
}

// ---------------------------------------------------------------------------
// Per-node: z[h][s] = dot(x[n,s,:], wq[h,:]); a = softmax(leaky_relu(z,0.2), s);
// xbar[h][n][i] = sum_s a[h][s] * x[n,s,i]
__global__ void attn_kernel(const float* __restrict__ x, const float* __restrict__ wq,
                            float* __restrict__ xbar) {
    __shared__ float xl[2560];
    __shared__ float wql[2048];
    __shared__ float zp[20][8];
    __shared__ float al[20];
    int n = blockIdx.x;
    int tid = threadIdx.x;
    const float* xr = x + (size_t)n * 2560;
    for (int i = tid; i < 2560; i += 256) xl[i] = xr[i];
    for (int i = tid; i < 2048; i += 256) wql[i] = wq[i];
    __syncthreads();
    if (tid < 160) {
        int p = tid >> 3, l8 = tid & 7;
        int h = p / 5, s = p % 5;
        const float* xs_ = xl + s * 512 + l8 * 64;
        const float* wr = wql + h * 512 + l8 * 64;
        float acc = 0.f;
        #pragma unroll 8
        for (int i = 0; i < 64; i++) acc += xs_[i] * wr[i];
        zp[p][l8] = acc;
    }
    __syncthreads();
    if (tid < 20) {
        float z = 0.f;
        #pragma unroll
        for (int j = 0; j < 8; j++) z += zp[tid][j];
        al[tid] = (z >= 0.f) ? z : 0.2f * z;   // leaky_relu slope 0.2
    }
    __syncthreads();
    if (tid < 4) {
        float m = -1e30f;
        #pragma unroll
        for (int s = 0; s < 5; s++) m = fmaxf(m, al[tid * 5 + s]);
        float e[5]; float sum = 0.f;
        #pragma unroll
        for (int s = 0; s < 5; s++) { e[s] = __expf(al[tid * 5 + s] - m); sum += e[s]; }
        float r = 1.f / sum;
        #pragma unroll
        for (int s = 0; s < 5; s++) al[tid * 5 + s] = e[s] * r;
    }
    __syncthreads();
    for (int i = tid; i < 512; i += 256) {
        #pragma unroll
        for (int h = 0; h < 4; h++) {
            float v = 0.f;
            #pragma unroll
            for (int s = 0; s < 5; s++) v += al[h * 5 + s] * xl[s * 512 + i];
            xbar[((size_t)h * NSPOT + n) * 512 + i] = v;
        }
    }
}

// ---------------------------------------------------------------------------
// Generic fp32 GEMM: C[M,N] = A[M,K](lda) @ B[K,N](ldb), C has ldc.
// 64x64 tile, 256 threads, 4x4 micro-tile, K-chunk 16.
#define GTM 64
#define GTN 64
#define GTK 16
__global__ __launch_bounds__(256) void gemm_kernel(
    const float* __restrict__ A, int lda,
    const float* __restrict__ B, int ldb,
    float* __restrict__ C, int ldc,
    int M, int N, int K) {
    __shared__ float Ast[GTK][GTM + 4];
    __shared__ float Bs[GTK][GTN + 4];
    int tid = threadIdx.x;
    int tx = tid & 15, ty = tid >> 4;
    int rowbase = blockIdx.x * GTM;
    int colbase = blockIdx.y * GTN;
    int arow = tid >> 2;           // 0..63
    int akq  = (tid & 3) * 4;      // 0,4,8,12
    int brow = tid >> 4;           // 0..15
    int bcq  = (tid & 15) * 4;     // 0..60
    float acc[4][4] = {};
    for (int k0 = 0; k0 < K; k0 += GTK) {
        // stage A (transposed into LDS)
        float4 av = make_float4(0.f, 0.f, 0.f, 0.f);
        int gr = rowbase + arow;
        if (gr < M) {
            int k = k0 + akq;
            if (k + 3 < K) {
                av = *reinterpret_cast<const float4*>(A + (size_t)gr * lda + k);
            } else {
                float t0 = (k + 0 < K) ? A[(size_t)gr * lda + k + 0] : 0.f;
                float t1 = (k + 1 < K) ? A[(size_t)gr * lda + k + 1] : 0.f;
                float t2 = (k + 2 < K) ? A[(size_t)gr * lda + k + 2] : 0.f;
                float t3 = (k + 3 < K) ? A[(size_t)gr * lda + k + 3] : 0.f;
                av = make_float4(t0, t1, t2, t3);
            }
        }
        Ast[akq + 0][arow] = av.x;
        Ast[akq + 1][arow] = av.y;
        Ast[akq + 2][arow] = av.z;
        Ast[akq + 3][arow] = av.w;
        // stage B
        float4 bv = make_float4(0.f, 0.f, 0.f, 0.f);
        int gk = k0 + brow;
        if (gk < K) bv = *reinterpret_cast<const float4*>(B + (size_t)gk * ldb + colbase + bcq);
        *reinterpret_cast<float4*>(&Bs[brow][bcq]) = bv;
        __syncthreads();
        #pragma unroll
        for (int kk = 0; kk < GTK; kk++) {
            float4 a4 = *reinterpret_cast<const float4*>(&Ast[kk][ty * 4]);
            float4 b4 = *reinterpret_cast<const float4*>(&Bs[kk][tx * 4]);
            acc[0][0] += a4.x * b4.x; acc[0][1] += a4.x * b4.y; acc[0][2] += a4.x * b4.z; acc[0][3] += a4.x * b4.w;
            acc[1][0] += a4.y * b4.x; acc[1][1] += a4.y * b4.y; acc[1][2] += a4.y * b4.z; acc[1][3] += a4.y * b4.w;
            acc[2][0] += a4.z * b4.x; acc[2][1] += a4.z * b4.y; acc[2][2] += a4.z * b4.z; acc[2][3] += a4.z * b4.w;
            acc[3][0] += a4.w * b4.x; acc[3][1] += a4.w * b4.y; acc[3][2] += a4.w * b4.z; acc[3][3] += a4.w * b4.w;
        }
        __syncthreads();
    }
    #pragma unroll
    for (int r = 0; r < 4; r++) {
        int gr = rowbase + ty * 4 + r;
        if (gr < M) {
            float4 o = make_float4(acc[r][0], acc[r][1], acc[r][2], acc[r][3]);
            *reinterpret_cast<float4*>(C + (size_t)gr * ldc + colbase + tx * 4) = o;
        }
    }
}

// ---------------------------------------------------------------------------
// Scatter-add: one wave per edge; acc[tgt] += msg[src]; cnt[tgt] += 1
__global__ void scatter_kernel(const float* __restrict__ msg,
                               const int* __restrict__ src, const int* __restrict__ tgt,
                               int E, float* __restrict__ acc, float* __restrict__ cnt) {
    int e = blockIdx.x * 4 + (threadIdx.x >> 6);
    if (e >= E) return;
    int lane = threadIdx.x & 63;
    int s = src[e], t = tgt[e];
    const float* m = msg + (size_t)s * HID;
    float* a = acc + (size_t)t * HID;
    #pragma unroll
    for (int j = 0; j < 4; j++) atomicAdd(&a[lane + j * 64], m[lane + j * 64]);
    if (lane == 0) atomicAdd(&cnt[t], 1.0f);
}

// ---------------------------------------------------------------------------
__global__ void combine_spot(const float* __restrict__ Sa, const float* __restrict__ Sb,
                             const float* __restrict__ accH, const float* __restrict__ cntH,
                             const float* __restrict__ accD, const float* __restrict__ cntD,
                             float* __restrict__ out) {
    int idx = blockIdx.x * 256 + threadIdx.x;
    int n = idx >> 8;
    float v = Sa[idx] + Sb[idx]
            + accH[idx] / fmaxf(cntH[n], 1.f)
            + accD[idx] / fmaxf(cntD[n], 1.f);
    out[idx] = fmaxf(v * 0.5f, 0.f);
}

__global__ void combine1(const float* __restrict__ S, const float* __restrict__ acc,
                         const float* __restrict__ cnt, float* __restrict__ out) {
    int idx = blockIdx.x * 256 + threadIdx.x;
    int n = idx >> 8;
    float v = S[idx] + acc[idx] / fmaxf(cnt[n], 1.f);
    out[idx] = fmaxf(v, 0.f);
}

// ---------------------------------------------------------------------------
__global__ void mean_kernel(const float* __restrict__ a, const float* __restrict__ b,
                            float* __restrict__ out, int n4) {
    int i = blockIdx.x * 256 + threadIdx.x;
    if (i >= n4) return;
    float4 x = reinterpret_cast<const float4*>(a)[i];
    float4 y = reinterpret_cast<const float4*>(b)[i];
    reinterpret_cast<float4*>(out)[i] =
        make_float4((x.x + y.x) * 0.5f, (x.y + y.y) * 0.5f, (x.z + y.z) * 0.5f, (x.w + y.w) * 0.5f);
}

// ---------------------------------------------------------------------------
// out[row] = dot(X[row,:256], w) + b ; one wave per row
__global__ void rowdot_kernel(const float* __restrict__ X, const float* __restrict__ w,
                              const float* __restrict__ b, float* __restrict__ out, int M) {
    int row = blockIdx.x * 4 + (threadIdx.x >> 6);
    if (row >= M) return;
    int lane = threadIdx.x & 63;
    const float* x = X + (size_t)row * HID;
    float s = 0.f;
    #pragma unroll
    for (int j = 0; j < 4; j++) s += x[lane + j * 64] * w[lane + j * 64];
    #pragma unroll
    for (int off = 32; off > 0; off >>= 1) s += __shfl_down(s, off, 64);
    if (lane == 0) out[row] = s + b[0];
}

// ---------------------------------------------------------------------------
extern "C" void kernel_launch(void* const* d_in, const int* in_sizes, int n_in,
                              void* d_out, int out_size, void* d_ws, size_t ws_size,
                              hipStream_t stream) {
    const float* x_spot   = (const float*)d_in[0];
    const float* x_city   = (const float*)d_in[1];
    const float* x_word   = (const float*)d_in[2];
    const float* W_att    = (const float*)d_in[3];
    const float* q_att    = (const float*)d_in[4];
    const float* w1_has_s   = (const float*)d_in[5];
    const float* w1_has_t   = (const float*)d_in[6];
    const float* w1_in_s    = (const float*)d_in[7];
    const float* w1_in_t    = (const float*)d_in[8];
    const float* w1_desc_s  = (const float*)d_in[9];
    const float* w1_desc_t  = (const float*)d_in[10];
    const float* w1_rdesc_s = (const float*)d_in[11];
    const float* w1_rdesc_t = (const float*)d_in[12];
    const float* w2_has_s   = (const float*)d_in[13];
    const float* w2_has_t   = (const float*)d_in[14];
    const float* w2_in_s    = (const float*)d_in[15];
    const float* w2_in_t    = (const float*)d_in[16];
    const float* w2_desc_s  = (const float*)d_in[17];
    const float* w2_desc_t  = (const float*)d_in[18];
    const float* w2_rdesc_s = (const float*)d_in[19];
    const float* w2_rdesc_t = (const float*)d_in[20];
    const float* wl_spot = (const float*)d_in[21];
    const float* wl_city = (const float*)d_in[22];
    const float* wl_word = (const float*)d_in[23];
    const float* bl_spot = (const float*)d_in[24];
    const float* bl_city = (const float*)d_in[25];
    const float* bl_word = (const float*)d_in[26];
    const int* e_has_src   = (const int*)d_in[27];
    const int* e_has_tgt   = (const int*)d_in[28];
    const int* e_in_src    = (const int*)d_in[29];
    const int* e_in_tgt    = (const int*)d_in[30];
    const int* e_desc_src  = (const int*)d_in[31];
    const int* e_desc_tgt  = (const int*)d_in[32];
    const int* e_rdesc_src = (const int*)d_in[33];
    const int* e_rdesc_tgt = (const int*)d_in[34];
    const int E_has   = in_sizes[27];
    const int E_in    = in_sizes[29];
    const int E_desc  = in_sizes[31];
    const int E_rdesc = in_sizes[33];

    float* out = (float*)d_out;
    float* wsf = (float*)d_ws;

    // ---- workspace layout (floats) ----
    size_t o = 0;
    float* wqb = wsf + o; o += 2048;
    float* xs  = wsf + o; o += (size_t)NSPOT * 512;            // 10,240,000
    // region A: xbar aliases all post-attention buffers
    size_t regA = o;
    float* xbar = wsf + regA;                                  // 4*20000*512 = 20,971,520
    o = regA;
    float* P_has   = wsf + o; o += (size_t)NCITY * HID;        // msg tables
    float* P_in    = wsf + o; o += (size_t)NSPOT * HID;
    float* P_desc  = wsf + o; o += (size_t)NWORD * HID;
    float* P_rdesc = wsf + o; o += (size_t)NSPOT * HID;
    float* Sa = wsf + o; o += (size_t)NSPOT * HID;             // self terms
    float* Sb = wsf + o; o += (size_t)NSPOT * HID;
    float* Sc = wsf + o; o += (size_t)NCITY * HID;
    float* Sw = wsf + o; o += (size_t)NWORD * HID;
    size_t acc_off = o;                                        // contiguous acc+cnt for memset
    float* acc_has   = wsf + o; o += (size_t)NSPOT * HID;
    float* acc_desc  = wsf + o; o += (size_t)NSPOT * HID;
    float* acc_in    = wsf + o; o += (size_t)NCITY * HID;
    float* acc_rdesc = wsf + o; o += (size_t)NWORD * HID;
    float* cnt_has   = wsf + o; o += NSPOT;
    float* cnt_desc  = wsf + o; o += NSPOT;
    float* cnt_in    = wsf + o; o += NCITY;
    float* cnt_rdesc = wsf + o; o += NWORD;
    size_t acc_bytes = (o - acc_off) * sizeof(float);
    float* s1  = wsf + o; o += (size_t)NSPOT * HID;
    float* c1  = wsf + o; o += (size_t)NCITY * HID;
    float* wd1 = wsf + o; o += (size_t)NWORD * HID;
    float* s2  = wsf + o; o += (size_t)NSPOT * HID;
    float* c2  = wsf + o; o += (size_t)NCITY * HID;
    float* wd2 = wsf + o; o += (size_t)NWORD * HID;
    (void)ws_size; (void)n_in; (void)out_size;

    auto gemm = [&](const float* A, int lda, const float* B, int ldb,
                    float* C, int ldc, int M, int N, int K) {
        dim3 g((M + GTM - 1) / GTM, N / GTN);
        hipLaunchKernelGGL(gemm_kernel, g, dim3(256), 0, stream, A, lda, B, ldb, C, ldc, M, N, K);
    };
    auto scatter = [&](const float* msg, const int* src, const int* tgt, int E,
                       float* acc, float* cnt) {
        hipLaunchKernelGGL(scatter_kernel, dim3((E + 3) / 4), dim3(256), 0, stream,
                           msg, src, tgt, E, acc, cnt);
    };

    // ---- attention ----
    hipLaunchKernelGGL(wq_kernel, dim3(8), dim3(256), 0, stream, W_att, q_att, wqb);
    hipLaunchKernelGGL(attn_kernel, dim3(NSPOT), dim3(256), 0, stream, x_spot, wqb, xbar);
    for (int h = 0; h < 4; h++) {
        gemm(xbar + (size_t)h * NSPOT * 512, 512,
             W_att + (size_t)h * 512 * 128, 128,
             xs + h * 128, 512, NSPOT, 128, 512);
    }

    // ---- layer 1 GEMMs ----
    gemm(x_city, 128, w1_has_s,   HID, P_has,   HID, NCITY, HID, 128);
    gemm(xs,     512, w1_has_t,   HID, Sa,      HID, NSPOT, HID, 512);
    gemm(xs,     512, w1_in_s,    HID, P_in,    HID, NSPOT, HID, 512);
    gemm(x_city, 128, w1_in_t,    HID, Sc,      HID, NCITY, HID, 128);
    gemm(x_word, 300, w1_desc_s,  HID, P_desc,  HID, NWORD, HID, 300);
    gemm(xs,     512, w1_desc_t,  HID, Sb,      HID, NSPOT, HID, 512);
    gemm(xs,     512, w1_rdesc_s, HID, P_rdesc, HID, NSPOT, HID, 512);
    gemm(x_word, 300, w1_rdesc_t, HID, Sw,      HID, NWORD, HID, 300);

    hipMemsetAsync(wsf + acc_off, 0, acc_bytes, stream);
    scatter(P_has,   e_has_src,   e_has_tgt,   E_has,   acc_has,   cnt_has);
    scatter(P_desc,  e_desc_src,  e_desc_tgt,  E_desc,  acc_desc,  cnt_desc);
    scatter(P_in,    e_in_src,    e_in_tgt,    E_in,    acc_in,    cnt_in);
    scatter(P_rdesc, e_rdesc_src, e_rdesc_tgt, E_rdesc, acc_rdesc, cnt_rdesc);

    hipLaunchKernelGGL(combine_spot, dim3(NSPOT), dim3(256), 0, stream,
                       Sa, Sb, acc_has, cnt_has, acc_desc, cnt_desc, s1);
    hipLaunchKernelGGL(combine1, dim3(NCITY), dim3(256), 0, stream, Sc, acc_in, cnt_in, c1);
    hipLaunchKernelGGL(combine1, dim3(NWORD), dim3(256), 0, stream, Sw, acc_rdesc, cnt_rdesc, wd1);

    // ---- layer 2 GEMMs ----
    gemm(c1,  HID, w2_has_s,   HID, P_has,   HID, NCITY, HID, HID);
    gemm(s1,  HID, w2_has_t,   HID, Sa,      HID, NSPOT, HID, HID);
    gemm(s1,  HID, w2_in_s,    HID, P_in,    HID, NSPOT, HID, HID);
    gemm(c1,  HID, w2_in_t,    HID, Sc,      HID, NCITY, HID, HID);
    gemm(wd1, HID, w2_desc_s,  HID, P_desc,  HID, NWORD, HID, HID);
    gemm(s1,  HID, w2_desc_t,  HID, Sb,      HID, NSPOT, HID, HID);
    gemm(s1,  HID, w2_rdesc_s, HID, P_rdesc, HID, NSPOT, HID, HID);
    gemm(wd1, HID, w2_rdesc_t, HID, Sw,      HID, NWORD, HID, HID);

    hipMemsetAsync(wsf + acc_off, 0, acc_bytes, stream);
    scatter(P_has,   e_has_src,   e_has_tgt,   E_has,   acc_has,   cnt_has);
    scatter(P_desc,  e_desc_src,  e_desc_tgt,  E_desc,  acc_desc,  cnt_desc);
    scatter(P_in,    e_in_src,    e_in_tgt,    E_in,    acc_in,    cnt_in);
    scatter(P_rdesc, e_rdesc_src, e_rdesc_tgt, E_rdesc, acc_rdesc, cnt_rdesc);

    hipLaunchKernelGGL(combine_spot, dim3(NSPOT), dim3(256), 0, stream,
                       Sa, Sb, acc_has, cnt_has, acc_desc, cnt_desc, s2);
    hipLaunchKernelGGL(combine1, dim3(NCITY), dim3(256), 0, stream, Sc, acc_in, cnt_in, c2);
    hipLaunchKernelGGL(combine1, dim3(NWORD), dim3(256), 0, stream, Sw, acc_rdesc, cnt_rdesc, wd2);

    // ---- outputs ----
    float* out0 = out;
    float* out1 = out + (size_t)NSPOT * HID;
    float* out2 = out1 + (size_t)NCITY * HID;
    float* out3 = out2 + (size_t)NWORD * HID;
    float* out4 = out3 + NSPOT;
    float* out5 = out4 + NCITY;
    int n4s = NSPOT * HID / 4, n4c = NCITY * HID / 4, n4w = NWORD * HID / 4;
    hipLaunchKernelGGL(mean_kernel, dim3((n4s + 255) / 256), dim3(256), 0, stream, s1, s2, out0, n4s);
    hipLaunchKernelGGL(mean_kernel, dim3((n4c + 255) / 256), dim3(256), 0, stream, c1, c2, out1, n4c);
    hipLaunchKernelGGL(mean_kernel, dim3((n4w + 255) / 256), dim3(256), 0, stream, wd1, wd2, out2, n4w);
    hipLaunchKernelGGL(rowdot_kernel, dim3((NSPOT + 3) / 4), dim3(256), 0, stream, s2, wl_spot, bl_spot, out3, NSPOT);
    hipLaunchKernelGGL(rowdot_kernel, dim3((NCITY + 3) / 4), dim3(256), 0, stream, c2, wl_city, bl_city, out4, NCITY);
    hipLaunchKernelGGL(rowdot_kernel, dim3((NWORD + 3) / 4), dim3(256), 0, stream, wd2, wl_word, bl_word, out5, NWORD);
}

// Round 2
// 2197.463 us; speedup vs baseline: 1.5544x; 1.5544x over previous
//
#include <hip/hip_runtime.h>

#define HID 256
#define NSPOT 20000
#define NCITY 2000
#define NWORD 20000

// ---------------------------------------------------------------------------
// wq[h][i] = sum_o W_att[h][i][o] * q_att[h][o]
__global__ void wq_kernel(const float* __restrict__ W, const float* __restrict__ q,
                          float* __restrict__ wq) {
    int idx = blockIdx.x * 256 + threadIdx.x;   // 4*512 = 2048
    if (idx >= 2048) return;
    int h = idx >> 9, i = idx & 511;
    const float* Wr = W + ((size_t)h * 512 + i) * 128;
    const float* qr = q + h * 128;
    float s = 0.f;
    #pragma unroll 4
    for (int o = 0; o < 128; o++) s += Wr[o] * qr[o];
    wq[idx] = s;
}

// ---------------------------------------------------------------------------
// Per-node: z[h][s] = dot(x[n,s,:], wq[h,:]); a = softmax(leaky_relu(z,0.2), s);
// xbar[h][n][i] = sum_s a[h][s] * x[n,s,i]
__global__ void attn_kernel(const float* __restrict__ x, const float* __restrict__ wq,
                            float* __restrict__ xbar) {
    __shared__ float xl[2560];
    __shared__ float wql[2048];
    __shared__ float zp[20][8];
    __shared__ float al[20];
    int n = blockIdx.x;
    int tid = threadIdx.x;
    const float* xr = x + (size_t)n * 2560;
    for (int i = tid; i < 2560; i += 256) xl[i] = xr[i];
    for (int i = tid; i < 2048; i += 256) wql[i] = wq[i];
    __syncthreads();
    if (tid < 160) {
        int p = tid >> 3, l8 = tid & 7;
        int h = p / 5, s = p % 5;
        const float* xs_ = xl + s * 512 + l8 * 64;
        const float* wr = wql + h * 512 + l8 * 64;
        float acc = 0.f;
        #pragma unroll 8
        for (int i = 0; i < 64; i++) acc += xs_[i] * wr[i];
        zp[p][l8] = acc;
    }
    __syncthreads();
    if (tid < 20) {
        float z = 0.f;
        #pragma unroll
        for (int j = 0; j < 8; j++) z += zp[tid][j];
        al[tid] = (z >= 0.f) ? z : 0.2f * z;   // leaky_relu slope 0.2
    }
    __syncthreads();
    if (tid < 4) {
        float m = -1e30f;
        #pragma unroll
        for (int s = 0; s < 5; s++) m = fmaxf(m, al[tid * 5 + s]);
        float e[5]; float sum = 0.f;
        #pragma unroll
        for (int s = 0; s < 5; s++) { e[s] = __expf(al[tid * 5 + s] - m); sum += e[s]; }
        float r = 1.f / sum;
        #pragma unroll
        for (int s = 0; s < 5; s++) al[tid * 5 + s] = e[s] * r;
    }
    __syncthreads();
    for (int i = tid; i < 512; i += 256) {
        #pragma unroll
        for (int h = 0; h < 4; h++) {
            float v = 0.f;
            #pragma unroll
            for (int s = 0; s < 5; s++) v += al[h * 5 + s] * xl[s * 512 + i];
            xbar[((size_t)h * NSPOT + n) * 512 + i] = v;
        }
    }
}

// ---------------------------------------------------------------------------
// Generic fp32 GEMM: C[M,N] = A[M,K](lda) @ B[K,N](ldb), C has ldc.
#define GTM 64
#define GTN 64
#define GTK 16
__global__ __launch_bounds__(256) void gemm_kernel(
    const float* __restrict__ A, int lda,
    const float* __restrict__ B, int ldb,
    float* __restrict__ C, int ldc,
    int M, int N, int K) {
    __shared__ float Ast[GTK][GTM + 4];
    __shared__ float Bs[GTK][GTN + 4];
    int tid = threadIdx.x;
    int tx = tid & 15, ty = tid >> 4;
    int rowbase = blockIdx.x * GTM;
    int colbase = blockIdx.y * GTN;
    int arow = tid >> 2;           // 0..63
    int akq  = (tid & 3) * 4;      // 0,4,8,12
    int brow = tid >> 4;           // 0..15
    int bcq  = (tid & 15) * 4;     // 0..60
    float acc[4][4] = {};
    for (int k0 = 0; k0 < K; k0 += GTK) {
        float4 av = make_float4(0.f, 0.f, 0.f, 0.f);
        int gr = rowbase + arow;
        if (gr < M) {
            int k = k0 + akq;
            if (k + 3 < K) {
                av = *reinterpret_cast<const float4*>(A + (size_t)gr * lda + k);
            } else {
                float t0 = (k + 0 < K) ? A[(size_t)gr * lda + k + 0] : 0.f;
                float t1 = (k + 1 < K) ? A[(size_t)gr * lda + k + 1] : 0.f;
                float t2 = (k + 2 < K) ? A[(size_t)gr * lda + k + 2] : 0.f;
                float t3 = (k + 3 < K) ? A[(size_t)gr * lda + k + 3] : 0.f;
                av = make_float4(t0, t1, t2, t3);
            }
        }
        Ast[akq + 0][arow] = av.x;
        Ast[akq + 1][arow] = av.y;
        Ast[akq + 2][arow] = av.z;
        Ast[akq + 3][arow] = av.w;
        float4 bv = make_float4(0.f, 0.f, 0.f, 0.f);
        int gk = k0 + brow;
        if (gk < K) bv = *reinterpret_cast<const float4*>(B + (size_t)gk * ldb + colbase + bcq);
        *reinterpret_cast<float4*>(&Bs[brow][bcq]) = bv;
        __syncthreads();
        #pragma unroll
        for (int kk = 0; kk < GTK; kk++) {
            float4 a4 = *reinterpret_cast<const float4*>(&Ast[kk][ty * 4]);
            float4 b4 = *reinterpret_cast<const float4*>(&Bs[kk][tx * 4]);
            acc[0][0] += a4.x * b4.x; acc[0][1] += a4.x * b4.y; acc[0][2] += a4.x * b4.z; acc[0][3] += a4.x * b4.w;
            acc[1][0] += a4.y * b4.x; acc[1][1] += a4.y * b4.y; acc[1][2] += a4.y * b4.z; acc[1][3] += a4.y * b4.w;
            acc[2][0] += a4.z * b4.x; acc[2][1] += a4.z * b4.y; acc[2][2] += a4.z * b4.z; acc[2][3] += a4.z * b4.w;
            acc[3][0] += a4.w * b4.x; acc[3][1] += a4.w * b4.y; acc[3][2] += a4.w * b4.z; acc[3][3] += a4.w * b4.w;
        }
        __syncthreads();
    }
    #pragma unroll
    for (int r = 0; r < 4; r++) {
        int gr = rowbase + ty * 4 + r;
        if (gr < M) {
            float4 o = make_float4(acc[r][0], acc[r][1], acc[r][2], acc[r][3]);
            *reinterpret_cast<float4*>(C + (size_t)gr * ldc + colbase + tx * 4) = o;
        }
    }
}

// ---------------------------------------------------------------------------
// CSR build: histogram -> exclusive scan -> fill (src ids grouped by target)
__global__ void hist_kernel(const int* __restrict__ tgt, int E, int* __restrict__ deg) {
    int e = blockIdx.x * 256 + threadIdx.x;
    if (e < E) atomicAdd(&deg[tgt[e]], 1);
}

__global__ void scan_kernel(const int* __restrict__ deg, int* __restrict__ rowptr, int n) {
    // single block, 256 threads
    __shared__ int partx[257];
    __shared__ int part[256];
    int tid = threadIdx.x;
    int chunk = (n + 255) / 256;
    int lo = tid * chunk;
    int hi = lo + chunk; if (hi > n) hi = n;
    int s = 0;
    for (int i = lo; i < hi; i++) s += deg[i];
    part[tid] = s;
    __syncthreads();
    if (tid == 0) {
        int acc = 0;
        for (int i = 0; i < 256; i++) { partx[i] = acc; acc += part[i]; }
        partx[256] = acc;
    }
    __syncthreads();
    int acc = partx[tid];
    for (int i = lo; i < hi; i++) { rowptr[i] = acc; acc += deg[i]; }
    if (tid == 0) rowptr[n] = partx[256];
}

__global__ void fill_kernel(const int* __restrict__ src, const int* __restrict__ tgt, int E,
                            int* __restrict__ cursor, int* __restrict__ csr_src) {
    int e = blockIdx.x * 256 + threadIdx.x;
    if (e >= E) return;
    int t = tgt[e];
    int pos = atomicAdd(&cursor[t], 1);
    csr_src[pos] = src[e];
}

// ---------------------------------------------------------------------------
// Segmented mean: one block per target row, thread d owns dim d. No atomics.
__global__ __launch_bounds__(256) void agg_mean_kernel(
    const float* __restrict__ msg, const int* __restrict__ rowptr,
    const int* __restrict__ csr_src, float* __restrict__ outmean) {
    int t = blockIdx.x;
    int d = threadIdx.x;
    int lo = rowptr[t], hi = rowptr[t + 1];
    float acc = 0.f;
    int i = lo;
    for (; i + 4 <= hi; i += 4) {
        int s0 = csr_src[i], s1 = csr_src[i + 1], s2 = csr_src[i + 2], s3 = csr_src[i + 3];
        float m0 = msg[(size_t)s0 * HID + d];
        float m1 = msg[(size_t)s1 * HID + d];
        float m2 = msg[(size_t)s2 * HID + d];
        float m3 = msg[(size_t)s3 * HID + d];
        acc += m0 + m1 + m2 + m3;
    }
    for (; i < hi; i++) acc += msg[(size_t)csr_src[i] * HID + d];
    float deg = (float)(hi - lo);
    outmean[(size_t)t * HID + d] = acc / fmaxf(deg, 1.f);
}

// ---------------------------------------------------------------------------
__global__ void combine_spot(const float* __restrict__ Sa, const float* __restrict__ Sb,
                             const float* __restrict__ mH, const float* __restrict__ mD,
                             float* __restrict__ out) {
    int idx = blockIdx.x * 256 + threadIdx.x;
    float v = Sa[idx] + Sb[idx] + mH[idx] + mD[idx];
    out[idx] = fmaxf(v * 0.5f, 0.f);
}

__global__ void combine1(const float* __restrict__ S, const float* __restrict__ m,
                         float* __restrict__ out) {
    int idx = blockIdx.x * 256 + threadIdx.x;
    float v = S[idx] + m[idx];
    out[idx] = fmaxf(v, 0.f);
}

// ---------------------------------------------------------------------------
__global__ void mean_kernel(const float* __restrict__ a, const float* __restrict__ b,
                            float* __restrict__ out, int n4) {
    int i = blockIdx.x * 256 + threadIdx.x;
    if (i >= n4) return;
    float4 x = reinterpret_cast<const float4*>(a)[i];
    float4 y = reinterpret_cast<const float4*>(b)[i];
    reinterpret_cast<float4*>(out)[i] =
        make_float4((x.x + y.x) * 0.5f, (x.y + y.y) * 0.5f, (x.z + y.z) * 0.5f, (x.w + y.w) * 0.5f);
}

// ---------------------------------------------------------------------------
__global__ void rowdot_kernel(const float* __restrict__ X, const float* __restrict__ w,
                              const float* __restrict__ b, float* __restrict__ out, int M) {
    int row = blockIdx.x * 4 + (threadIdx.x >> 6);
    if (row >= M) return;
    int lane = threadIdx.x & 63;
    const float* x = X + (size_t)row * HID;
    float s = 0.f;
    #pragma unroll
    for (int j = 0; j < 4; j++) s += x[lane + j * 64] * w[lane + j * 64];
    #pragma unroll
    for (int off = 32; off > 0; off >>= 1) s += __shfl_down(s, off, 64);
    if (lane == 0) out[row] = s + b[0];
}

// ---------------------------------------------------------------------------
extern "C" void kernel_launch(void* const* d_in, const int* in_sizes, int n_in,
                              void* d_out, int out_size, void* d_ws, size_t ws_size,
                              hipStream_t stream) {
    const float* x_spot   = (const float*)d_in[0];
    const float* x_city   = (const float*)d_in[1];
    const float* x_word   = (const float*)d_in[2];
    const float* W_att    = (const float*)d_in[3];
    const float* q_att    = (const float*)d_in[4];
    const float* w1_has_s   = (const float*)d_in[5];
    const float* w1_has_t   = (const float*)d_in[6];
    const float* w1_in_s    = (const float*)d_in[7];
    const float* w1_in_t    = (const float*)d_in[8];
    const float* w1_desc_s  = (const float*)d_in[9];
    const float* w1_desc_t  = (const float*)d_in[10];
    const float* w1_rdesc_s = (const float*)d_in[11];
    const float* w1_rdesc_t = (const float*)d_in[12];
    const float* w2_has_s   = (const float*)d_in[13];
    const float* w2_has_t   = (const float*)d_in[14];
    const float* w2_in_s    = (const float*)d_in[15];
    const float* w2_in_t    = (const float*)d_in[16];
    const float* w2_desc_s  = (const float*)d_in[17];
    const float* w2_desc_t  = (const float*)d_in[18];
    const float* w2_rdesc_s = (const float*)d_in[19];
    const float* w2_rdesc_t = (const float*)d_in[20];
    const float* wl_spot = (const float*)d_in[21];
    const float* wl_city = (const float*)d_in[22];
    const float* wl_word = (const float*)d_in[23];
    const float* bl_spot = (const float*)d_in[24];
    const float* bl_city = (const float*)d_in[25];
    const float* bl_word = (const float*)d_in[26];
    const int* e_has_src   = (const int*)d_in[27];
    const int* e_has_tgt   = (const int*)d_in[28];
    const int* e_in_src    = (const int*)d_in[29];
    const int* e_in_tgt    = (const int*)d_in[30];
    const int* e_desc_src  = (const int*)d_in[31];
    const int* e_desc_tgt  = (const int*)d_in[32];
    const int* e_rdesc_src = (const int*)d_in[33];
    const int* e_rdesc_tgt = (const int*)d_in[34];
    const int E_has   = in_sizes[27];
    const int E_in    = in_sizes[29];
    const int E_desc  = in_sizes[31];
    const int E_rdesc = in_sizes[33];

    float* out = (float*)d_out;
    float* wsf = (float*)d_ws;

    // ---- workspace layout (floats) ----
    size_t o = 0;
    float* wqb = wsf + o; o += 2048;
    float* xs  = wsf + o; o += (size_t)NSPOT * 512;
    // region A: xbar aliases post-attention buffers
    size_t regA = o;
    float* xbar = wsf + regA;                                  // 4*20000*512
    o = regA;
    float* P_has   = wsf + o; o += (size_t)NCITY * HID;
    float* P_in    = wsf + o; o += (size_t)NSPOT * HID;
    float* P_desc  = wsf + o; o += (size_t)NWORD * HID;
    float* P_rdesc = wsf + o; o += (size_t)NSPOT * HID;
    float* Sa = wsf + o; o += (size_t)NSPOT * HID;
    float* Sb = wsf + o; o += (size_t)NSPOT * HID;
    float* Sc = wsf + o; o += (size_t)NCITY * HID;
    float* Sw = wsf + o; o += (size_t)NWORD * HID;
    float* m_has   = wsf + o; o += (size_t)NSPOT * HID;        // mean tables
    float* m_desc  = wsf + o; o += (size_t)NSPOT * HID;
    float* m_in    = wsf + o; o += (size_t)NCITY * HID;
    float* m_rdesc = wsf + o; o += (size_t)NWORD * HID;
    float* s1  = wsf + o; o += (size_t)NSPOT * HID;
    float* c1  = wsf + o; o += (size_t)NCITY * HID;
    float* wd1 = wsf + o; o += (size_t)NWORD * HID;
    float* s2  = wsf + o; o += (size_t)NSPOT * HID;
    float* c2  = wsf + o; o += (size_t)NCITY * HID;
    float* wd2 = wsf + o; o += (size_t)NWORD * HID;
    // ensure region past xbar end for the CSR ints (xbar spans 4*NSPOT*512 from regA)
    size_t xbar_end = regA + (size_t)4 * NSPOT * 512;
    if (o < xbar_end) o = xbar_end;
    // CSR arrays (int), never aliased
    int* wsi = (int*)(wsf + o);
    size_t io = 0;
    int* deg_has    = wsi + io; io += NSPOT;
    int* deg_desc   = wsi + io; io += NSPOT;
    int* deg_in     = wsi + io; io += NCITY;
    int* deg_rdesc  = wsi + io; io += NWORD;
    size_t deg_bytes = io * sizeof(int);
    int* rp_has     = wsi + io; io += NSPOT + 1;
    int* rp_desc    = wsi + io; io += NSPOT + 1;
    int* rp_in      = wsi + io; io += NCITY + 1;
    int* rp_rdesc   = wsi + io; io += NWORD + 1;
    int* cur_has    = wsi + io; io += NSPOT + 1;
    int* cur_desc   = wsi + io; io += NSPOT + 1;
    int* cur_in     = wsi + io; io += NCITY + 1;
    int* cur_rdesc  = wsi + io; io += NWORD + 1;
    int* cs_has     = wsi + io; io += E_has;
    int* cs_desc    = wsi + io; io += E_desc;
    int* cs_in      = wsi + io; io += E_in;
    int* cs_rdesc   = wsi + io; io += E_rdesc;
    (void)ws_size; (void)n_in; (void)out_size;

    auto gemm = [&](const float* A, int lda, const float* B, int ldb,
                    float* C, int ldc, int M, int N, int K) {
        dim3 g((M + GTM - 1) / GTM, N / GTN);
        hipLaunchKernelGGL(gemm_kernel, g, dim3(256), 0, stream, A, lda, B, ldb, C, ldc, M, N, K);
    };
    auto build_csr = [&](const int* src, const int* tgt, int E, int n,
                         int* deg, int* rp, int* cur, int* cs) {
        hipLaunchKernelGGL(hist_kernel, dim3((E + 255) / 256), dim3(256), 0, stream, tgt, E, deg);
        hipLaunchKernelGGL(scan_kernel, dim3(1), dim3(256), 0, stream, deg, rp, n);
        hipMemcpyAsync(cur, rp, (n + 1) * sizeof(int), hipMemcpyDeviceToDevice, stream);
        hipLaunchKernelGGL(fill_kernel, dim3((E + 255) / 256), dim3(256), 0, stream, src, tgt, E, cur, cs);
    };
    auto agg = [&](const float* msg, const int* rp, const int* cs, int n, float* outm) {
        hipLaunchKernelGGL(agg_mean_kernel, dim3(n), dim3(256), 0, stream, msg, rp, cs, outm);
    };

    // ---- CSR build (once, reused by both layers) ----
    hipMemsetAsync((void*)deg_has, 0, deg_bytes, stream);
    build_csr(e_has_src,   e_has_tgt,   E_has,   NSPOT, deg_has,   rp_has,   cur_has,   cs_has);
    build_csr(e_desc_src,  e_desc_tgt,  E_desc,  NSPOT, deg_desc,  rp_desc,  cur_desc,  cs_desc);
    build_csr(e_in_src,    e_in_tgt,    E_in,    NCITY, deg_in,    rp_in,    cur_in,    cs_in);
    build_csr(e_rdesc_src, e_rdesc_tgt, E_rdesc, NWORD, deg_rdesc, rp_rdesc, cur_rdesc, cs_rdesc);

    // ---- attention ----
    hipLaunchKernelGGL(wq_kernel, dim3(8), dim3(256), 0, stream, W_att, q_att, wqb);
    hipLaunchKernelGGL(attn_kernel, dim3(NSPOT), dim3(256), 0, stream, x_spot, wqb, xbar);
    for (int h = 0; h < 4; h++) {
        gemm(xbar + (size_t)h * NSPOT * 512, 512,
             W_att + (size_t)h * 512 * 128, 128,
             xs + h * 128, 512, NSPOT, 128, 512);
    }

    // ---- layer 1 GEMMs ----
    gemm(x_city, 128, w1_has_s,   HID, P_has,   HID, NCITY, HID, 128);
    gemm(xs,     512, w1_has_t,   HID, Sa,      HID, NSPOT, HID, 512);
    gemm(xs,     512, w1_in_s,    HID, P_in,    HID, NSPOT, HID, 512);
    gemm(x_city, 128, w1_in_t,    HID, Sc,      HID, NCITY, HID, 128);
    gemm(x_word, 300, w1_desc_s,  HID, P_desc,  HID, NWORD, HID, 300);
    gemm(xs,     512, w1_desc_t,  HID, Sb,      HID, NSPOT, HID, 512);
    gemm(xs,     512, w1_rdesc_s, HID, P_rdesc, HID, NSPOT, HID, 512);
    gemm(x_word, 300, w1_rdesc_t, HID, Sw,      HID, NWORD, HID, 300);

    agg(P_has,   rp_has,   cs_has,   NSPOT, m_has);
    agg(P_desc,  rp_desc,  cs_desc,  NSPOT, m_desc);
    agg(P_in,    rp_in,    cs_in,    NCITY, m_in);
    agg(P_rdesc, rp_rdesc, cs_rdesc, NWORD, m_rdesc);

    hipLaunchKernelGGL(combine_spot, dim3(NSPOT), dim3(256), 0, stream, Sa, Sb, m_has, m_desc, s1);
    hipLaunchKernelGGL(combine1, dim3(NCITY), dim3(256), 0, stream, Sc, m_in, c1);
    hipLaunchKernelGGL(combine1, dim3(NWORD), dim3(256), 0, stream, Sw, m_rdesc, wd1);

    // ---- layer 2 GEMMs ----
    gemm(c1,  HID, w2_has_s,   HID, P_has,   HID, NCITY, HID, HID);
    gemm(s1,  HID, w2_has_t,   HID, Sa,      HID, NSPOT, HID, HID);
    gemm(s1,  HID, w2_in_s,    HID, P_in,    HID, NSPOT, HID, HID);
    gemm(c1,  HID, w2_in_t,    HID, Sc,      HID, NCITY, HID, HID);
    gemm(wd1, HID, w2_desc_s,  HID, P_desc,  HID, NWORD, HID, HID);
    gemm(s1,  HID, w2_desc_t,  HID, Sb,      HID, NSPOT, HID, HID);
    gemm(s1,  HID, w2_rdesc_s, HID, P_rdesc, HID, NSPOT, HID, HID);
    gemm(wd1, HID, w2_rdesc_t, HID, Sw,      HID, NWORD, HID, HID);

    agg(P_has,   rp_has,   cs_has,   NSPOT, m_has);
    agg(P_desc,  rp_desc,  cs_desc,  NSPOT, m_desc);
    agg(P_in,    rp_in,    cs_in,    NCITY, m_in);
    agg(P_rdesc, rp_rdesc, cs_rdesc, NWORD, m_rdesc);

    hipLaunchKernelGGL(combine_spot, dim3(NSPOT), dim3(256), 0, stream, Sa, Sb, m_has, m_desc, s2);
    hipLaunchKernelGGL(combine1, dim3(NCITY), dim3(256), 0, stream, Sc, m_in, c2);
    hipLaunchKernelGGL(combine1, dim3(NWORD), dim3(256), 0, stream, Sw, m_rdesc, wd2);

    // ---- outputs ----
    float* out0 = out;
    float* out1 = out + (size_t)NSPOT * HID;
    float* out2 = out1 + (size_t)NCITY * HID;
    float* out3 = out2 + (size_t)NWORD * HID;
    float* out4 = out3 + NSPOT;
    float* out5 = out4 + NCITY;
    int n4s = NSPOT * HID / 4, n4c = NCITY * HID / 4, n4w = NWORD * HID / 4;
    hipLaunchKernelGGL(mean_kernel, dim3((n4s + 255) / 256), dim3(256), 0, stream, s1, s2, out0, n4s);
    hipLaunchKernelGGL(mean_kernel, dim3((n4c + 255) / 256), dim3(256), 0, stream, c1, c2, out1, n4c);
    hipLaunchKernelGGL(mean_kernel, dim3((n4w + 255) / 256), dim3(256), 0, stream, wd1, wd2, out2, n4w);
    hipLaunchKernelGGL(rowdot_kernel, dim3((NSPOT + 3) / 4), dim3(256), 0, stream, s2, wl_spot, bl_spot, out3, NSPOT);
    hipLaunchKernelGGL(rowdot_kernel, dim3((NCITY + 3) / 4), dim3(256), 0, stream, c2, wl_city, bl_city, out4, NCITY);
    hipLaunchKernelGGL(rowdot_kernel, dim3((NWORD + 3) / 4), dim3(256), 0, stream, wd2, wl_word, bl_word, out5, NWORD);
}

// Round 3
// 1272.690 us; speedup vs baseline: 2.6839x; 1.7266x over previous
//
#include <hip/hip_runtime.h>
#include <hip/hip_bf16.h>

#define HID 256
#define NSPOT 20000
#define NCITY 2000
#define NWORD 20000

typedef __attribute__((ext_vector_type(8))) short bhalf8;
typedef __attribute__((ext_vector_type(4))) float floatx4;

// ---------------------------------------------------------------------------
// wq[h][i] = sum_o W_att[h][i][o] * q_att[h][o]
__global__ void wq_kernel(const float* __restrict__ W, const float* __restrict__ q,
                          float* __restrict__ wq) {
    int idx = blockIdx.x * 256 + threadIdx.x;   // 4*512 = 2048
    if (idx >= 2048) return;
    int h = idx >> 9, i = idx & 511;
    const float* Wr = W + ((size_t)h * 512 + i) * 128;
    const float* qr = q + h * 128;
    float s = 0.f;
    #pragma unroll 4
    for (int o = 0; o < 128; o++) s += Wr[o] * qr[o];
    wq[idx] = s;
}

// ---------------------------------------------------------------------------
// Per-node attention: scores via wave-reduction (conflict-free LDS), softmax,
// blend -> xbar bf16 [h][n][512].
__global__ __launch_bounds__(256) void attn_kernel(const float* __restrict__ x,
                                                   const float* __restrict__ wq,
                                                   __hip_bfloat16* __restrict__ xbar) {
    __shared__ float xl[2560];
    __shared__ float al[4][8];
    int n = blockIdx.x;
    int tid = threadIdx.x;
    int wave = tid >> 6, lane = tid & 63;
    const float4* xr4 = (const float4*)(x + (size_t)n * 2560);
    for (int i = tid; i < 640; i += 256) ((float4*)xl)[i] = xr4[i];
    __syncthreads();
    // wave w = head w; 5 dot-products of length 512 over 64 lanes
    const float* wqh = wq + wave * 512;
    for (int s = 0; s < 5; s++) {
        float a = 0.f;
        #pragma unroll
        for (int j = 0; j < 8; j++)
            a += xl[s * 512 + lane + j * 64] * wqh[lane + j * 64];
        #pragma unroll
        for (int off = 32; off > 0; off >>= 1) a += __shfl_down(a, off, 64);
        if (lane == 0) al[wave][s] = a;
    }
    __syncthreads();
    if (tid < 4) {
        float z[5]; float m = -1e30f;
        #pragma unroll
        for (int s = 0; s < 5; s++) {
            float v = al[tid][s];
            v = (v >= 0.f) ? v : 0.2f * v;    // leaky_relu 0.2
            z[s] = v; m = fmaxf(m, v);
        }
        float e[5]; float sum = 0.f;
        #pragma unroll
        for (int s = 0; s < 5; s++) { e[s] = __expf(z[s] - m); sum += e[s]; }
        float r = 1.f / sum;
        #pragma unroll
        for (int s = 0; s < 5; s++) al[tid][s] = e[s] * r;
    }
    __syncthreads();
    float a0 = al[wave][0], a1 = al[wave][1], a2 = al[wave][2], a3 = al[wave][3], a4 = al[wave][4];
    __hip_bfloat16* xo = xbar + ((size_t)wave * NSPOT + n) * 512;
    #pragma unroll
    for (int j = 0; j < 8; j++) {
        int i = lane + j * 64;
        float v = a0 * xl[i] + a1 * xl[512 + i] + a2 * xl[1024 + i] + a3 * xl[1536 + i] + a4 * xl[2048 + i];
        xo[i] = __float2bfloat16(v);
    }
}

// ---------------------------------------------------------------------------
// bf16 MFMA GEMM: C[M,N] = A[M,K] @ Bt[N,K]^T.  128x128 tile, 4 waves (64x64
// each as 4x4 of 16x16), K%32==0.  Optional fp32 C and/or bf16 Cb outputs.
// Batched over blockIdx.z via element strides.
#define KP 40   // padded halfword stride in LDS (80B: 2-way bank aliasing = free)
__global__ __launch_bounds__(256) void gemm_bf16(
    const __hip_bfloat16* __restrict__ A, int lda, long sA,
    const __hip_bfloat16* __restrict__ Bt, int ldb, long sB,
    float* __restrict__ C, int ldc,
    __hip_bfloat16* __restrict__ Cb, int ldcb, long sCb,
    int M, int N, int K) {
    __shared__ short As[128 * KP];
    __shared__ short Bs[128 * KP];
    int z = blockIdx.z;
    A += (size_t)z * sA;
    Bt += (size_t)z * sB;
    if (Cb) Cb += (size_t)z * sCb;
    int tid = threadIdx.x;
    int wave = tid >> 6, lane = tid & 63;
    int wr = wave & 1, wc = wave >> 1;
    int quad = lane >> 4, l16 = lane & 15;
    int rowbase = blockIdx.x * 128;
    int colbase = blockIdx.y * 128;
    int srow = tid >> 2;            // 0..63
    int skoff = (tid & 3) * 8;      // 0,8,16,24
    floatx4 acc[4][4];
    #pragma unroll
    for (int i = 0; i < 4; i++)
        #pragma unroll
        for (int j = 0; j < 4; j++)
            acc[i][j] = (floatx4){0.f, 0.f, 0.f, 0.f};

    for (int k0 = 0; k0 < K; k0 += 32) {
        #pragma unroll
        for (int i = 0; i < 2; i++) {
            int r = srow + i * 64;
            int gr = rowbase + r;
            int4 va = make_int4(0, 0, 0, 0);
            if (gr < M) va = *(const int4*)(A + (size_t)gr * lda + k0 + skoff);
            *(int4*)(As + r * KP + skoff) = va;
            int4 vb = *(const int4*)(Bt + (size_t)(colbase + r) * ldb + k0 + skoff);
            *(int4*)(Bs + r * KP + skoff) = vb;
        }
        __syncthreads();
        bhalf8 af[4], bfr[4];
        #pragma unroll
        for (int rt = 0; rt < 4; rt++)
            af[rt] = *(const bhalf8*)(As + (wr * 64 + rt * 16 + l16) * KP + quad * 8);
        #pragma unroll
        for (int ct = 0; ct < 4; ct++)
            bfr[ct] = *(const bhalf8*)(Bs + (wc * 64 + ct * 16 + l16) * KP + quad * 8);
        #pragma unroll
        for (int rt = 0; rt < 4; rt++)
            #pragma unroll
            for (int ct = 0; ct < 4; ct++)
                acc[rt][ct] = __builtin_amdgcn_mfma_f32_16x16x32_bf16(af[rt], bfr[ct], acc[rt][ct], 0, 0, 0);
        __syncthreads();
    }
    // epilogue: D row = quad*4 + reg, col = lane&15
    #pragma unroll
    for (int rt = 0; rt < 4; rt++) {
        #pragma unroll
        for (int r = 0; r < 4; r++) {
            int grow = rowbase + wr * 64 + rt * 16 + quad * 4 + r;
            if (grow < M) {
                #pragma unroll
                for (int ct = 0; ct < 4; ct++) {
                    int gcol = colbase + wc * 64 + ct * 16 + l16;
                    float v = acc[rt][ct][r];
                    if (C)  C[(size_t)grow * ldc + gcol] = v;
                    if (Cb) Cb[(size_t)grow * ldcb + gcol] = __float2bfloat16(v);
                }
            }
        }
    }
}

// ---------------------------------------------------------------------------
// Batched transpose-cast: in fp32 [K][N] -> out bf16 [N][Kp], zero-pad K..Kp.
struct TDesc { const float* in; __hip_bfloat16* out; int K; int N; int Kp; };
struct TDesc8 { TDesc d[8]; };
__global__ void transpose_cast_kernel(TDesc8 descs) {
    TDesc dsc = descs.d[blockIdx.z];
    __shared__ float tile[32][33];
    int k0 = blockIdx.x * 32, n0 = blockIdx.y * 32;
    if (k0 >= dsc.Kp || n0 >= dsc.N) return;
    int tn = threadIdx.x & 31, t8 = threadIdx.x >> 5;
    #pragma unroll
    for (int i = 0; i < 4; i++) {
        int k = k0 + t8 * 4 + i;
        float v = 0.f;
        if (k < dsc.K && n0 + tn < dsc.N) v = dsc.in[(size_t)k * dsc.N + n0 + tn];
        tile[t8 * 4 + i][tn] = v;
    }
    __syncthreads();
    int kk = threadIdx.x & 31, n8 = threadIdx.x >> 5;
    #pragma unroll
    for (int i = 0; i < 4; i++) {
        int n = n0 + n8 * 4 + i;
        int k = k0 + kk;
        if (n < dsc.N && k < dsc.Kp)
            dsc.out[(size_t)n * dsc.Kp + k] = __float2bfloat16(tile[kk][n8 * 4 + i]);
    }
}

// cast fp32 -> bf16 (flat)
__global__ void cast_kernel(const float* __restrict__ in, __hip_bfloat16* __restrict__ out, int n) {
    int i = blockIdx.x * 256 + threadIdx.x;
    if (i < n) out[i] = __float2bfloat16(in[i]);
}

// cast fp32 [rows][K] -> bf16 [rows][Kp] zero-padded
__global__ void cast_pad_kernel(const float* __restrict__ in, __hip_bfloat16* __restrict__ out,
                                int rows, int K, int Kp) {
    int idx = blockIdx.x * 256 + threadIdx.x;
    if (idx >= rows * Kp) return;
    int r = idx / Kp, k = idx - r * Kp;
    out[idx] = (k < K) ? __float2bfloat16(in[(size_t)r * K + k]) : __float2bfloat16(0.f);
}

// ---------------------------------------------------------------------------
// CSR build: histogram -> exclusive scan -> fill
__global__ void hist_kernel(const int* __restrict__ tgt, int E, int* __restrict__ deg) {
    int e = blockIdx.x * 256 + threadIdx.x;
    if (e < E) atomicAdd(&deg[tgt[e]], 1);
}

__global__ void scan_kernel(const int* __restrict__ deg, int* __restrict__ rowptr, int n) {
    __shared__ int partx[257];
    __shared__ int part[256];
    int tid = threadIdx.x;
    int chunk = (n + 255) / 256;
    int lo = tid * chunk;
    int hi = lo + chunk; if (hi > n) hi = n;
    int s = 0;
    for (int i = lo; i < hi; i++) s += deg[i];
    part[tid] = s;
    __syncthreads();
    if (tid == 0) {
        int acc = 0;
        for (int i = 0; i < 256; i++) { partx[i] = acc; acc += part[i]; }
        partx[256] = acc;
    }
    __syncthreads();
    int acc = partx[tid];
    for (int i = lo; i < hi; i++) { rowptr[i] = acc; acc += deg[i]; }
    if (tid == 0) rowptr[n] = partx[256];
}

__global__ void fill_kernel(const int* __restrict__ src, const int* __restrict__ tgt, int E,
                            int* __restrict__ cursor, int* __restrict__ csr_src) {
    int e = blockIdx.x * 256 + threadIdx.x;
    if (e >= E) return;
    int t = tgt[e];
    int pos = atomicAdd(&cursor[t], 1);
    csr_src[pos] = src[e];
}

// ---------------------------------------------------------------------------
// Segmented mean over bf16 messages: one block per target row, thread d = dim d.
__global__ __launch_bounds__(256) void agg_mean_kernel(
    const __hip_bfloat16* __restrict__ msg, const int* __restrict__ rowptr,
    const int* __restrict__ csr_src, float* __restrict__ outmean) {
    int t = blockIdx.x;
    int d = threadIdx.x;
    int lo = rowptr[t], hi = rowptr[t + 1];
    float acc = 0.f;
    int i = lo;
    for (; i + 4 <= hi; i += 4) {
        int s0 = csr_src[i], s1 = csr_src[i + 1], s2 = csr_src[i + 2], s3 = csr_src[i + 3];
        float m0 = __bfloat162float(msg[(size_t)s0 * HID + d]);
        float m1 = __bfloat162float(msg[(size_t)s1 * HID + d]);
        float m2 = __bfloat162float(msg[(size_t)s2 * HID + d]);
        float m3 = __bfloat162float(msg[(size_t)s3 * HID + d]);
        acc += m0 + m1 + m2 + m3;
    }
    for (; i < hi; i++) acc += __bfloat162float(msg[(size_t)csr_src[i] * HID + d]);
    outmean[(size_t)t * HID + d] = acc / fmaxf((float)(hi - lo), 1.f);
}

// ---------------------------------------------------------------------------
// NOTE: no __restrict__ here — out may alias one of the mean inputs (same idx).
__global__ void combine_spot(const float* Sa, const float* Sb,
                             const float* mH, const float* mD,
                             float* out, __hip_bfloat16* outb) {
    int idx = blockIdx.x * 256 + threadIdx.x;
    float v = fmaxf((Sa[idx] + Sb[idx] + mH[idx] + mD[idx]) * 0.5f, 0.f);
    out[idx] = v;
    if (outb) outb[idx] = __float2bfloat16(v);
}

__global__ void combine1(const float* S, const float* m,
                         float* out, __hip_bfloat16* outb) {
    int idx = blockIdx.x * 256 + threadIdx.x;
    float v = fmaxf(S[idx] + m[idx], 0.f);
    out[idx] = v;
    if (outb) outb[idx] = __float2bfloat16(v);
}

// ---------------------------------------------------------------------------
__global__ void mean_kernel(const float* __restrict__ a, const float* __restrict__ b,
                            float* __restrict__ out, int n4) {
    int i = blockIdx.x * 256 + threadIdx.x;
    if (i >= n4) return;
    float4 x = reinterpret_cast<const float4*>(a)[i];
    float4 y = reinterpret_cast<const float4*>(b)[i];
    reinterpret_cast<float4*>(out)[i] =
        make_float4((x.x + y.x) * 0.5f, (x.y + y.y) * 0.5f, (x.z + y.z) * 0.5f, (x.w + y.w) * 0.5f);
}

__global__ void rowdot_kernel(const float* __restrict__ X, const float* __restrict__ w,
                              const float* __restrict__ b, float* __restrict__ out, int M) {
    int row = blockIdx.x * 4 + (threadIdx.x >> 6);
    if (row >= M) return;
    int lane = threadIdx.x & 63;
    const float* x = X + (size_t)row * HID;
    float s = 0.f;
    #pragma unroll
    for (int j = 0; j < 4; j++) s += x[lane + j * 64] * w[lane + j * 64];
    #pragma unroll
    for (int off = 32; off > 0; off >>= 1) s += __shfl_down(s, off, 64);
    if (lane == 0) out[row] = s + b[0];
}

// ---------------------------------------------------------------------------
extern "C" void kernel_launch(void* const* d_in, const int* in_sizes, int n_in,
                              void* d_out, int out_size, void* d_ws, size_t ws_size,
                              hipStream_t stream) {
    const float* x_spot   = (const float*)d_in[0];
    const float* x_city   = (const float*)d_in[1];
    const float* x_word   = (const float*)d_in[2];
    const float* W_att    = (const float*)d_in[3];
    const float* q_att    = (const float*)d_in[4];
    const float* w1[8] = { (const float*)d_in[5], (const float*)d_in[6], (const float*)d_in[7],
                           (const float*)d_in[8], (const float*)d_in[9], (const float*)d_in[10],
                           (const float*)d_in[11], (const float*)d_in[12] };
    const float* w2[8] = { (const float*)d_in[13], (const float*)d_in[14], (const float*)d_in[15],
                           (const float*)d_in[16], (const float*)d_in[17], (const float*)d_in[18],
                           (const float*)d_in[19], (const float*)d_in[20] };
    const float* wl_spot = (const float*)d_in[21];
    const float* wl_city = (const float*)d_in[22];
    const float* wl_word = (const float*)d_in[23];
    const float* bl_spot = (const float*)d_in[24];
    const float* bl_city = (const float*)d_in[25];
    const float* bl_word = (const float*)d_in[26];
    const int* e_has_src   = (const int*)d_in[27];
    const int* e_has_tgt   = (const int*)d_in[28];
    const int* e_in_src    = (const int*)d_in[29];
    const int* e_in_tgt    = (const int*)d_in[30];
    const int* e_desc_src  = (const int*)d_in[31];
    const int* e_desc_tgt  = (const int*)d_in[32];
    const int* e_rdesc_src = (const int*)d_in[33];
    const int* e_rdesc_tgt = (const int*)d_in[34];
    const int E_has   = in_sizes[27];
    const int E_in    = in_sizes[29];
    const int E_desc  = in_sizes[31];
    const int E_rdesc = in_sizes[33];

    float* out = (float*)d_out;
    float* wsf = (float*)d_ws;
    typedef __hip_bfloat16 bf;

    // ---- workspace layout (units of float; bf16 arrays use half) ----
    size_t o = 0;
    auto alloc = [&](size_t nfloats) { float* p = wsf + o; o += (nfloats + 15) & ~(size_t)15; return p; };
    float* wqb       = alloc(2048);
    bf* xs_bf        = (bf*)alloc((size_t)NSPOT * 512 / 2);
    bf* x_city_bf    = (bf*)alloc((size_t)NCITY * 128 / 2);
    bf* x_word_bf    = (bf*)alloc((size_t)NWORD * 320 / 2);
    bf* Wt_att       = (bf*)alloc((size_t)4 * 128 * 512 / 2);
    // L1 transposed weights: [N=256][Kp]
    int K1[8]  = {128, 512, 512, 128, 300, 512, 512, 300};
    int Kp1[8] = {128, 512, 512, 128, 320, 512, 512, 320};
    bf* Wt1[8];
    for (int i = 0; i < 8; i++) Wt1[i] = (bf*)alloc((size_t)256 * Kp1[i] / 2);
    bf* Wt2[8];
    for (int i = 0; i < 8; i++) Wt2[i] = (bf*)alloc((size_t)256 * 256 / 2);
    float* Sa = alloc((size_t)NSPOT * HID);
    float* Sb = alloc((size_t)NSPOT * HID);
    float* Sc = alloc((size_t)NCITY * HID);
    float* Sw = alloc((size_t)NWORD * HID);
    float* m_has   = alloc((size_t)NSPOT * HID);   // layer-2: also s2 (element-wise in-place safe)
    float* m_desc  = alloc((size_t)NSPOT * HID);
    float* m_in    = alloc((size_t)NCITY * HID);   // also c2
    float* m_rdesc = alloc((size_t)NWORD * HID);   // also wd2
    float* s1  = alloc((size_t)NSPOT * HID);
    float* c1  = alloc((size_t)NCITY * HID);
    float* wd1 = alloc((size_t)NWORD * HID);
    // region X: xbar (attention, dead after projection GEMMs) hosts P_* and s1b trio
    size_t regX = o;
    bf* xbar_bf = (bf*)(wsf + regX);                         // 4*NSPOT*512 bf16 = 20.48M floats
    {
        size_t oo = regX;
        auto allocX = [&](size_t nfloats) { float* p = wsf + oo; oo += (nfloats + 15) & ~(size_t)15; return p; };
        (void)allocX;
    }
    size_t ox = regX;
    auto allocX = [&](size_t nfloats) { float* p = wsf + ox; ox += (nfloats + 15) & ~(size_t)15; return p; };
    bf* P_has_bf   = (bf*)allocX((size_t)NCITY * HID / 2);
    bf* P_in_bf    = (bf*)allocX((size_t)NSPOT * HID / 2);
    bf* P_desc_bf  = (bf*)allocX((size_t)NWORD * HID / 2);
    bf* P_rdesc_bf = (bf*)allocX((size_t)NSPOT * HID / 2);
    bf* s1b = (bf*)allocX((size_t)NSPOT * HID / 2);
    bf* c1b = (bf*)allocX((size_t)NCITY * HID / 2);
    bf* wd1b = (bf*)allocX((size_t)NWORD * HID / 2);
    o = regX + (size_t)4 * NSPOT * 512 / 2;                  // past xbar end (covers allocX region)
    float* s2  = m_has;
    float* c2  = m_in;
    float* wd2 = m_rdesc;
    // CSR ints
    int* wsi = (int*)(wsf + o);
    size_t io = 0;
    int* deg_has    = wsi + io; io += NSPOT;
    int* deg_desc   = wsi + io; io += NSPOT;
    int* deg_in     = wsi + io; io += NCITY;
    int* deg_rdesc  = wsi + io; io += NWORD;
    size_t deg_bytes = io * sizeof(int);
    int* rp_has     = wsi + io; io += NSPOT + 1;
    int* rp_desc    = wsi + io; io += NSPOT + 1;
    int* rp_in      = wsi + io; io += NCITY + 1;
    int* rp_rdesc   = wsi + io; io += NWORD + 1;
    int* cur_has    = wsi + io; io += NSPOT + 1;
    int* cur_desc   = wsi + io; io += NSPOT + 1;
    int* cur_in     = wsi + io; io += NCITY + 1;
    int* cur_rdesc  = wsi + io; io += NWORD + 1;
    int* cs_has     = wsi + io; io += E_has;
    int* cs_desc    = wsi + io; io += E_desc;
    int* cs_in      = wsi + io; io += E_in;
    int* cs_rdesc   = wsi + io; io += E_rdesc;
    (void)ws_size; (void)n_in; (void)out_size;

    auto gemm = [&](const bf* A, int lda, long sA, const bf* Bt, int ldb, long sB,
                    float* C, int ldc, bf* Cb, int ldcb, long sCb,
                    int M, int N, int K, int batch) {
        dim3 g((M + 127) / 128, N / 128, batch);
        hipLaunchKernelGGL(gemm_bf16, g, dim3(256), 0, stream,
                           A, lda, sA, Bt, ldb, sB, C, ldc, Cb, ldcb, sCb, M, N, K);
    };
    auto build_csr = [&](const int* src, const int* tgt, int E, int n,
                         int* deg, int* rp, int* cur, int* cs) {
        hipLaunchKernelGGL(hist_kernel, dim3((E + 255) / 256), dim3(256), 0, stream, tgt, E, deg);
        hipLaunchKernelGGL(scan_kernel, dim3(1), dim3(256), 0, stream, deg, rp, n);
        hipMemcpyAsync(cur, rp, (n + 1) * sizeof(int), hipMemcpyDeviceToDevice, stream);
        hipLaunchKernelGGL(fill_kernel, dim3((E + 255) / 256), dim3(256), 0, stream, src, tgt, E, cur, cs);
    };
    auto agg = [&](const bf* msg, const int* rp, const int* cs, int n, float* outm) {
        hipLaunchKernelGGL(agg_mean_kernel, dim3(n), dim3(256), 0, stream, msg, rp, cs, outm);
    };

    // ---- weight transpose-casts + input casts ----
    {
        TDesc8 t{};
        for (int i = 0; i < 4; i++)
            t.d[i] = TDesc{ W_att + (size_t)i * 512 * 128, Wt_att + (size_t)i * 128 * 512, 512, 128, 512 };
        hipLaunchKernelGGL(transpose_cast_kernel, dim3(16, 4, 4), dim3(256), 0, stream, t);
    }
    {
        TDesc8 t{};
        for (int i = 0; i < 8; i++) t.d[i] = TDesc{ w1[i], Wt1[i], K1[i], 256, Kp1[i] };
        hipLaunchKernelGGL(transpose_cast_kernel, dim3(16, 8, 8), dim3(256), 0, stream, t);
    }
    {
        TDesc8 t{};
        for (int i = 0; i < 8; i++) t.d[i] = TDesc{ w2[i], Wt2[i], 256, 256, 256 };
        hipLaunchKernelGGL(transpose_cast_kernel, dim3(8, 8, 8), dim3(256), 0, stream, t);
    }
    hipLaunchKernelGGL(cast_kernel, dim3((NCITY * 128 + 255) / 256), dim3(256), 0, stream,
                       x_city, x_city_bf, NCITY * 128);
    hipLaunchKernelGGL(cast_pad_kernel, dim3((NWORD * 320 + 255) / 256), dim3(256), 0, stream,
                       x_word, x_word_bf, NWORD, 300, 320);

    // ---- CSR build (reused by both layers) ----
    hipMemsetAsync((void*)deg_has, 0, deg_bytes, stream);
    build_csr(e_has_src,   e_has_tgt,   E_has,   NSPOT, deg_has,   rp_has,   cur_has,   cs_has);
    build_csr(e_desc_src,  e_desc_tgt,  E_desc,  NSPOT, deg_desc,  rp_desc,  cur_desc,  cs_desc);
    build_csr(e_in_src,    e_in_tgt,    E_in,    NCITY, deg_in,    rp_in,    cur_in,    cs_in);
    build_csr(e_rdesc_src, e_rdesc_tgt, E_rdesc, NWORD, deg_rdesc, rp_rdesc, cur_rdesc, cs_rdesc);

    // ---- attention ----
    hipLaunchKernelGGL(wq_kernel, dim3(8), dim3(256), 0, stream, W_att, q_att, wqb);
    hipLaunchKernelGGL(attn_kernel, dim3(NSPOT), dim3(256), 0, stream, x_spot, wqb, xbar_bf);
    // projection: 4 heads batched; xs[n][h*128..] = xbar[h] @ W_att[h]
    gemm(xbar_bf, 512, (long)NSPOT * 512, Wt_att, 512, (long)128 * 512,
         nullptr, 0, xs_bf, 512, 128, NSPOT, 128, 512, 4);

    // ---- layer 1 GEMMs ----
    gemm(x_city_bf, 128, 0, Wt1[0], 128, 0, nullptr, 0, P_has_bf, HID, 0, NCITY, HID, 128, 1);
    gemm(xs_bf,     512, 0, Wt1[1], 512, 0, Sa, HID, nullptr, 0, 0, NSPOT, HID, 512, 1);
    gemm(xs_bf,     512, 0, Wt1[2], 512, 0, nullptr, 0, P_in_bf, HID, 0, NSPOT, HID, 512, 1);
    gemm(x_city_bf, 128, 0, Wt1[3], 128, 0, Sc, HID, nullptr, 0, 0, NCITY, HID, 128, 1);
    gemm(x_word_bf, 320, 0, Wt1[4], 320, 0, nullptr, 0, P_desc_bf, HID, 0, NWORD, HID, 320, 1);
    gemm(xs_bf,     512, 0, Wt1[5], 512, 0, Sb, HID, nullptr, 0, 0, NSPOT, HID, 512, 1);
    gemm(xs_bf,     512, 0, Wt1[6], 512, 0, nullptr, 0, P_rdesc_bf, HID, 0, NSPOT, HID, 512, 1);
    gemm(x_word_bf, 320, 0, Wt1[7], 320, 0, Sw, HID, nullptr, 0, 0, NWORD, HID, 320, 1);

    agg(P_has_bf,   rp_has,   cs_has,   NSPOT, m_has);
    agg(P_desc_bf,  rp_desc,  cs_desc,  NSPOT, m_desc);
    agg(P_in_bf,    rp_in,    cs_in,    NCITY, m_in);
    agg(P_rdesc_bf, rp_rdesc, cs_rdesc, NWORD, m_rdesc);

    hipLaunchKernelGGL(combine_spot, dim3(NSPOT), dim3(256), 0, stream, Sa, Sb, m_has, m_desc, s1, s1b);
    hipLaunchKernelGGL(combine1, dim3(NCITY), dim3(256), 0, stream, Sc, m_in, c1, c1b);
    hipLaunchKernelGGL(combine1, dim3(NWORD), dim3(256), 0, stream, Sw, m_rdesc, wd1, wd1b);

    // ---- layer 2 GEMMs ----
    gemm(c1b,  HID, 0, Wt2[0], HID, 0, nullptr, 0, P_has_bf, HID, 0, NCITY, HID, HID, 1);
    gemm(s1b,  HID, 0, Wt2[1], HID, 0, Sa, HID, nullptr, 0, 0, NSPOT, HID, HID, 1);
    gemm(s1b,  HID, 0, Wt2[2], HID, 0, nullptr, 0, P_in_bf, HID, 0, NSPOT, HID, HID, 1);
    gemm(c1b,  HID, 0, Wt2[3], HID, 0, Sc, HID, nullptr, 0, 0, NCITY, HID, HID, 1);
    gemm(wd1b, HID, 0, Wt2[4], HID, 0, nullptr, 0, P_desc_bf, HID, 0, NWORD, HID, HID, 1);
    gemm(s1b,  HID, 0, Wt2[5], HID, 0, Sb, HID, nullptr, 0, 0, NSPOT, HID, HID, 1);
    gemm(s1b,  HID, 0, Wt2[6], HID, 0, nullptr, 0, P_rdesc_bf, HID, 0, NSPOT, HID, HID, 1);
    gemm(wd1b, HID, 0, Wt2[7], HID, 0, Sw, HID, nullptr, 0, 0, NWORD, HID, HID, 1);

    agg(P_has_bf,   rp_has,   cs_has,   NSPOT, m_has);
    agg(P_desc_bf,  rp_desc,  cs_desc,  NSPOT, m_desc);
    agg(P_in_bf,    rp_in,    cs_in,    NCITY, m_in);
    agg(P_rdesc_bf, rp_rdesc, cs_rdesc, NWORD, m_rdesc);

    // s2/c2/wd2 alias m_has/m_in/m_rdesc: element-wise same-idx in-place (no restrict)
    hipLaunchKernelGGL(combine_spot, dim3(NSPOT), dim3(256), 0, stream, Sa, Sb, m_has, m_desc, s2, (bf*)nullptr);
    hipLaunchKernelGGL(combine1, dim3(NCITY), dim3(256), 0, stream, Sc, m_in, c2, (bf*)nullptr);
    hipLaunchKernelGGL(combine1, dim3(NWORD), dim3(256), 0, stream, Sw, m_rdesc, wd2, (bf*)nullptr);

    // ---- outputs ----
    float* out0 = out;
    float* out1 = out + (size_t)NSPOT * HID;
    float* out2 = out1 + (size_t)NCITY * HID;
    float* out3 = out2 + (size_t)NWORD * HID;
    float* out4 = out3 + NSPOT;
    float* out5 = out4 + NCITY;
    int n4s = NSPOT * HID / 4, n4c = NCITY * HID / 4, n4w = NWORD * HID / 4;
    hipLaunchKernelGGL(mean_kernel, dim3((n4s + 255) / 256), dim3(256), 0, stream, s1, s2, out0, n4s);
    hipLaunchKernelGGL(mean_kernel, dim3((n4c + 255) / 256), dim3(256), 0, stream, c1, c2, out1, n4c);
    hipLaunchKernelGGL(mean_kernel, dim3((n4w + 255) / 256), dim3(256), 0, stream, wd1, wd2, out2, n4w);
    hipLaunchKernelGGL(rowdot_kernel, dim3((NSPOT + 3) / 4), dim3(256), 0, stream, s2, wl_spot, bl_spot, out3, NSPOT);
    hipLaunchKernelGGL(rowdot_kernel, dim3((NCITY + 3) / 4), dim3(256), 0, stream, c2, wl_city, bl_city, out4, NCITY);
    hipLaunchKernelGGL(rowdot_kernel, dim3((NWORD + 3) / 4), dim3(256), 0, stream, wd2, wl_word, bl_word, out5, NWORD);
}